// Round 2
// baseline (52.753 us; speedup 1.0000x reference)
//
#include <hip/hip_runtime.h>
#include <hip/hip_bf16.h>

#define NUM_NODES 16384
#define NPG 8           // nodes per graph
#define NUM_EDGES 14336
#define EPG 7           // edges per graph (14336 / 2048)
#define NUM_RELS 64
#define DIM 128
#define BATCH 2048
#define EPS 1e-8f

// One block per query graph. 128 threads = one output dim each (2 waves).
// All edges are graph-local by construction (edge_index = g*8 + local).
__global__ __launch_bounds__(128) void rgcn_fused_kernel(
    const float* __restrict__ x,
    const float* __restrict__ basis,
    const float* __restrict__ root,
    const float* __restrict__ bias,
    const float* __restrict__ target,
    const int* __restrict__ edge_index,
    const int* __restrict__ edge_type,
    float* __restrict__ out)
{
    const int g = blockIdx.x;
    const int o = threadIdx.x;  // 0..127

    __shared__ float xs[NPG][DIM];   // 4 KB: this graph's 8 node feature rows
    __shared__ float red[6];         // cross-wave reduction scratch

    // ---- stage x rows: 1024 floats = 256 float4, 128 threads -> 2 each ----
    {
        const float4* xg = reinterpret_cast<const float4*>(x + (size_t)g * NPG * DIM);
        float4* xs4 = reinterpret_cast<float4*>(&xs[0][0]);
        xs4[o]       = xg[o];
        xs4[o + 128] = xg[o + 128];
    }
    __syncthreads();

    // ---- per-node accumulators: h1[n][o] = bias[o] + (x@root)[n][o] + msgs ----
    float acc[NPG];
    {
        const float b = bias[o];
        #pragma unroll
        for (int n = 0; n < NPG; ++n) acc[n] = b;
    }

    // root part: acc[n] += sum_d xs[n][d] * root[d*DIM + o]
    // root column loads are coalesced across the wave (consecutive o -> consecutive addr)
    for (int d4 = 0; d4 < DIM / 4; ++d4) {
        const float r0 = root[(d4 * 4 + 0) * DIM + o];
        const float r1 = root[(d4 * 4 + 1) * DIM + o];
        const float r2 = root[(d4 * 4 + 2) * DIM + o];
        const float r3 = root[(d4 * 4 + 3) * DIM + o];
        #pragma unroll
        for (int n = 0; n < NPG; ++n) {
            const float4 xv = reinterpret_cast<const float4*>(&xs[n][0])[d4];
            acc[n] += xv.x * r0 + xv.y * r1 + xv.z * r2 + xv.w * r3;
        }
    }

    // edge part: for each of the 7 edges, msg_o = xs[src] . basis[rel][:, o]
    {
        const int ebase = g * EPG;
        for (int e = 0; e < EPG; ++e) {
            const int ge  = ebase + e;
            const int src = edge_index[ge] - g * NPG;              // local src in [0,8)
            const int dst = edge_index[NUM_EDGES + ge] - g * NPG;  // local dst in [0,8)
            const int rel = edge_type[ge];
            const float* __restrict__ B = basis + (size_t)rel * DIM * DIM;
            float m = 0.f;
            for (int d4 = 0; d4 < DIM / 4; ++d4) {
                const float4 xv = reinterpret_cast<const float4*>(&xs[src][0])[d4];
                m += xv.x * B[(d4 * 4 + 0) * DIM + o];
                m += xv.y * B[(d4 * 4 + 1) * DIM + o];
                m += xv.z * B[(d4 * 4 + 2) * DIM + o];
                m += xv.w * B[(d4 * 4 + 3) * DIM + o];
            }
            // acc[dst] += m without dynamic register indexing (rule #20):
            #pragma unroll
            for (int n = 0; n < NPG; ++n) {
                acc[n] += (n == dst) ? m : 0.f;
            }
        }
    }

    // ---- relu + sum-pool over the graph's 8 nodes ----
    float p = 0.f;
    #pragma unroll
    for (int n = 0; n < NPG; ++n) p += fmaxf(acc[n], 0.f);

    // ---- cosine similarity vs target ----
    const float t = target[(size_t)g * DIM + o];
    float num_p = p * t;
    float na_p  = p * p;
    float nb_p  = t * t;

    // wave-level reduce (width 64)
    #pragma unroll
    for (int off = 32; off > 0; off >>= 1) {
        num_p += __shfl_down(num_p, off);
        na_p  += __shfl_down(na_p, off);
        nb_p  += __shfl_down(nb_p, off);
    }
    const int wave = o >> 6;
    const int lane = o & 63;
    if (lane == 0) {
        red[wave * 3 + 0] = num_p;
        red[wave * 3 + 1] = na_p;
        red[wave * 3 + 2] = nb_p;
    }
    __syncthreads();
    if (o == 0) {
        const float num = red[0] + red[3];
        const float na  = fmaxf(sqrtf(red[1] + red[4]), EPS);
        const float nb  = fmaxf(sqrtf(red[2] + red[5]), EPS);
        out[g] = num / (na * nb);
    }
}

extern "C" void kernel_launch(void* const* d_in, const int* in_sizes, int n_in,
                              void* d_out, int out_size, void* d_ws, size_t ws_size,
                              hipStream_t stream) {
    const float* x          = (const float*)d_in[0];
    const float* basis      = (const float*)d_in[1];
    const float* root       = (const float*)d_in[2];
    const float* bias       = (const float*)d_in[3];
    const float* target     = (const float*)d_in[4];
    const int*   edge_index = (const int*)d_in[5];
    const int*   edge_type  = (const int*)d_in[6];
    // d_in[7] = batch_idx (implicit: node / 8), unused

    float* out = (float*)d_out;

    rgcn_fused_kernel<<<BATCH, 128, 0, stream>>>(
        x, basis, root, bias, target, edge_index, edge_type, out);
}